// Round 2
// 152.192 us; speedup vs baseline: 1.0507x; 1.0507x over previous
//
#include <hip/hip_runtime.h>

// Gammatone filterbank, truncated-history formulation, packed-f32 inner loop.
// v2: STAGE-SKEWED cascade. The previous kernel evaluated all 4 one-pole
// sections at the same time index, giving a serial chain of 8 dependent
// packed FMAs per sample (~32-64 stall cycles) with only 1 wave/SIMD to
// hide it -> dependency-latency-bound. Here the stages are software-
// pipelined in time: at iteration i the registers hold
//   s1 = y1[i+2], s2 = y2[i+1], s3 = y3[i], s4 = y4[i-1]
// so the four stage updates of one iteration depend only on the PREVIOUS
// iteration's values and are mutually independent: 4 independent 2-FMA
// chains, 8 pk-FMAs of issue -> issue-bound, ~2-3x faster inner loop.
// Arithmetic per stage is operation-identical to v1 (bit-exact outputs).

typedef float f32x2 __attribute__((ext_vector_type(2)));

#define B_N    8
#define T_LEN  32000
#define C_CH   128
#define L_CHK  500
#define NB     64          // T_LEN / L_CHK
#define W_MAX  1024

// One skewed pipeline step, consuming x[i+3]:
//   s4 <- y4[i]   = c*y4[i-1] + y3[i]
//   s3 <- y3[i+1] = c*y3[i]   + y2[i+1]
//   s2 <- y2[i+2] = c*y2[i+1] + y1[i+2]
//   s1 <- y1[i+3] = c*y1[i+2] + x[i+3]
// All t's read pre-update values; the 4 (t,s) pairs are independent.
#define PSTEP(XR) do {                               \
    const f32x2 xin = {(XR), 0.f};                   \
    const f32x2 t4 = crr * s4 + s3;                  \
    const f32x2 t3 = crr * s3 + s2;                  \
    const f32x2 t2 = crr * s2 + s1;                  \
    const f32x2 t1 = crr * s1 + xin;                 \
    s4 = cni * s4.yx + t4;                           \
    s3 = cni * s3.yx + t3;                           \
    s2 = cni * s2.yx + t2;                           \
    s1 = cni * s1.yx + t1;                           \
} while (0)

__global__ __launch_bounds__(64) void gt_trunc(
    const float* __restrict__ x, const float* __restrict__ cre,
    const float* __restrict__ cim, const float* __restrict__ fac,
    float* __restrict__ out)
{
    __shared__ __align__(16) float xs[L_CHK + W_MAX + 8];
    const int g  = blockIdx.x;            // channel half (0: ch 0-63, 1: ch 64-127)
    const int k  = blockIdx.y;            // time chunk
    const int b  = blockIdx.z;            // batch
    const int c  = g * 64 + threadIdx.x;
    const int t0 = k * L_CHK;

    // Warm-up length from the largest-|c| channel of this half (channel g*64:
    // |c| decreases with channel index).
    const float cr0 = cre[g * 64], ci0 = cim[g * 64];
    const float negln = -0.5f * __logf(cr0 * cr0 + ci0 * ci0);   // -ln|c|
    int W = (int)ceilf(18.0f / negln) + 2;
    W = (W + 3) & ~3;                      // multiple of 4 (float4 LDS reads)
    if (W > W_MAX) W = W_MAX;
    int start = t0 - W;
    if (start < 0) start = 0;              // early chunks: zero init is exact
    const int n  = t0 + L_CHK - start;     // staged samples (multiple of 4)
    const int nw = t0 - start;             // warm-up steps (multiple of 4)

    // Stage x[start .. t0+L) into LDS at xs[1..n] (shifted by 1 so the
    // skewed consumption index i+3 lands on 16B-aligned float4 quads),
    // coalesced (256 B / wave instruction). Zero-fill 7 tail slots: the
    // last pipeline iterations consume up to x[n+2] which only feeds the
    // dead s1..s3 values, but must not be NaN garbage.
    const float* xb = x + (size_t)b * T_LEN + start;
    for (int i = threadIdx.x; i < n; i += 64) xs[i + 1] = xb[i];
    if (threadIdx.x < 7) xs[n + 1 + threadIdx.x] = 0.f;

    const float cr = cre[c], ci = cim[c], f = fac[c];
    const f32x2 crr = {cr, cr};
    const f32x2 cni = {-ci, ci};
    __syncthreads();

    // Pipeline fill in closed form from zero state (x0..x2 = xs[1..3]):
    //   s1 = y1[2], s2 = y2[1], s3 = y3[0], s4 = y4[-1] = 0.
    const f32x2 a0 = {xs[1], 0.f}, a1 = {xs[2], 0.f}, a2 = {xs[3], 0.f};
    f32x2 t, y11, s1, s2, s3, s4;
    t  = crr * a0  + a1;  y11 = cni * a0.yx  + t;   // y1[1]
    t  = crr * y11 + a2;  s1  = cni * y11.yx + t;   // y1[2]
    t  = crr * a0  + y11; s2  = cni * a0.yx  + t;   // y2[1]
    s3 = a0;                                         // y3[0] = x[0]
    s4 = (f32x2){0.f, 0.f};                          // y4[-1]

    // Warm-up (no stores), LDS reads software-pipelined one quad ahead.
    // Body at i consumes x[i+3 .. i+6] = xs[i+4 .. i+7].
    float4 cur = *(const float4*)&xs[4];
    for (int i = 0; i < nw; i += 4) {
        const float4 nxt = *(const float4*)&xs[i + 8];
        PSTEP(cur.x); PSTEP(cur.y); PSTEP(cur.z); PSTEP(cur.w);
        cur = nxt;
    }
    // loop exit leaves cur = xs[nw+4 .. nw+7]

    // Output region: after the step at iteration i, s4 = y4[i]; store for
    // i >= nw. One coalesced 256 B wave-store per time step; gain applied
    // at store (filter is linear).
    float* op = out + ((size_t)b * T_LEN + t0) * C_CH + c;
    for (int i = nw; i < nw + L_CHK; i += 4) {
        const float4 nxt = *(const float4*)&xs[i + 8];
        PSTEP(cur.x); op[0 * C_CH] = s4.x * f;
        PSTEP(cur.y); op[1 * C_CH] = s4.x * f;
        PSTEP(cur.z); op[2 * C_CH] = s4.x * f;
        PSTEP(cur.w); op[3 * C_CH] = s4.x * f;
        op += 4 * (size_t)C_CH;
        cur = nxt;
    }
}

extern "C" void kernel_launch(void* const* d_in, const int* in_sizes, int n_in,
                              void* d_out, int out_size, void* d_ws, size_t ws_size,
                              hipStream_t stream) {
    const float* x   = (const float*)d_in[0];
    const float* cre = (const float*)d_in[1];
    const float* cim = (const float*)d_in[2];
    const float* fac = (const float*)d_in[3];
    float* out = (float*)d_out;

    gt_trunc<<<dim3(2, NB, B_N), 64, 0, stream>>>(x, cre, cim, fac, out);
}